// Round 16
// baseline (359.123 us; speedup 1.0000x reference)
//
#include <hip/hip_runtime.h>
#include <hip/hip_bf16.h>
#include <string.h>

#define L 4096
#define D 256
#define H 8
#define DH 32

typedef __attribute__((ext_vector_type(8))) short bf16x8;
typedef __attribute__((ext_vector_type(4))) float f32x4;

#define LOG2E 1.4426950408889634f
#define RS (0.17677669529663688f * LOG2E)   // 1/sqrt(DH) * log2(e), folded into Q

__device__ __forceinline__ ushort f2bf(float f) {
    union { float f; unsigned int i; } v; v.f = f;
    unsigned int x = v.i;
    return (ushort)((x + 0x7fffu + ((x >> 16) & 1u)) >> 16);   // RNE
}
__device__ __forceinline__ bf16x8 cvt8(const float* p) {
    float4 a = *(const float4*)p;
    float4 b = *(const float4*)(p + 4);
    bf16x8 r;
    r[0] = (short)f2bf(a.x); r[1] = (short)f2bf(a.y);
    r[2] = (short)f2bf(a.z); r[3] = (short)f2bf(a.w);
    r[4] = (short)f2bf(b.x); r[5] = (short)f2bf(b.y);
    r[6] = (short)f2bf(b.z); r[7] = (short)f2bf(b.w);
    return r;
}
// pack two fp32 -> bf16x2 dword; native v_cvt_pk_bf16_f32 on gfx950
__device__ __forceinline__ unsigned int pkbf(float a, float b) {
    float2 t; t.x = a; t.y = b;
    __hip_bfloat162 r = __float22bfloat162_rn(t);
    unsigned int u; memcpy(&u, &r, 4);
    return u;
}

// sigma: logical key u (0..63) -> K storage row within its 64-block.
__device__ __forceinline__ int ksig(int u) {
    return 32 * (u >> 5) + 16 * ((u >> 2) & 1) + 4 * ((u >> 3) & 3) + (u & 3);
}

// Fragment-major (FM) layout for MFMA operand matrices (R rows x C cols bf16):
//   elem(r,c) at ((r>>4)*(C/8) + (c>>3))*128 + (r&15)*8 + (c&7)
// A wave's fragment load is ONE contiguous 1KB transaction (R8: -14.5 us).

// ---------------- Kernel 0: prepack (R15-identical) ----------------
// m2 payload: 2x 16-bit pair byte-offsets (e_i*14+e_j)*136 into the stride-17
// f32-PAIR LUT (8B entries). Dword positions unchanged.
__global__ __launch_bounds__(256) void pack_kernel(
        const int* __restrict__ mask, const float* __restrict__ x,
        const float* __restrict__ wi, const float* __restrict__ wo,
        unsigned int* __restrict__ m2, ushort* __restrict__ xb,
        ushort* __restrict__ wib, ushort* __restrict__ wob)
{
    const int b = blockIdx.x;
    const int tid = threadIdx.x;
    if (b < 512) {
        __shared__ unsigned int rb[8 * 1025];
        const int4* src = (const int4*)(mask + (size_t)b * 8 * 4096);
#pragma unroll
        for (int i = 0; i < 32; i++) {
            const int g = i * 256 + tid;
            int4 v = src[g];
            rb[(g >> 10) * 1025 + (g & 1023)] =
                ((unsigned int)(v.x & 15) << 4)  | ((unsigned int)(v.y & 15) << 12) |
                ((unsigned int)(v.z & 15) << 20) | ((unsigned int)(v.w & 15) << 28);
        }
        __syncthreads();
        const int t = b >> 1, half = b & 1;
#pragma unroll
        for (int i = 0; i < 32; i++) {
            const int dd = i * 256 + tid;
            const int nt = dd & 3, s = (dd >> 2) & 7, qd = (dd >> 5) & 3, kt = dd >> 7;
            const unsigned int w =
                rb[s * 1025 + kt * 16 + 8 * (nt >> 1) + 2 * qd + (nt & 1)];
            const unsigned int e0 = (w >> 4) & 15u, e1 = (w >> 12) & 15u;
            const unsigned int e2 = (w >> 20) & 15u, e3 = w >> 28;
            const unsigned int p01 = e0 * 14u + e1, p23 = e2 * 14u + e3;
            m2[(size_t)t * 16384 + kt * 256 + (qd * 16 + 8 * half + s) * 4 + nt] =
                (p01 * 136u) | ((p23 * 136u) << 16);
        }
    } else if (b < 1024) {
        const int g = (b - 512) * 256 + tid;
        const int l = g & 15, kd = (g >> 4) & 31, mg = g >> 9;
        ((bf16x8*)xb)[g] = cvt8(x + (mg * 16 + l) * 256 + kd * 8);
    } else if (b < 1120) {
        const int g = (b - 1024) * 256 + tid;           // 768x256 FM
        const int l = g & 15, kd = (g >> 4) & 31, mg = g >> 9;
        ((bf16x8*)wib)[g] = cvt8(wi + (mg * 16 + l) * 256 + kd * 8);
    } else {
        const int g = (b - 1120) * 256 + tid;           // 256x256 FM
        const int l = g & 15, kd = (g >> 4) & 31, mg = g >> 9;
        ((bf16x8*)wob)[g] = cvt8(wo + (mg * 16 + l) * 256 + kd * 8);
    }
}

// ---------------- Kernel 1: QKV projection (R15-identical) ----------------
__global__ __launch_bounds__(256) void qkv_kernel(
        const ushort* __restrict__ xb, const ushort* __restrict__ wb,
        const float* __restrict__ b,
        ushort* __restrict__ Qb, ushort* __restrict__ Kb, ushort* __restrict__ Vt)
{
    __shared__ ushort tile[64][72];   // 9.2 KB; row stride 144B (16B-aligned)

    const int lane = threadIdx.x & 63, wv = threadIdx.x >> 6;
    const int quad = lane >> 4, l15 = lane & 15;
    const int m0b = blockIdx.x * 64;
    const int by = blockIdx.y;            // 0-3: Q, 4-7: K, 8-11: V
    const int n0 = by * 64;
    const ushort* ap = xb + (size_t)(blockIdx.x * 4 + wv) * 4096 + l15 * 8;
    const ushort* bp = wb + (size_t)(by * 4) * 4096 + l15 * 8;

    f32x4 acc[4] = {};
    for (int ks = 0; ks < 8; ks++) {
        const int kdi = (ks * 4 + quad) * 128;
        bf16x8 af = *(const bf16x8*)(ap + kdi);
#pragma unroll
        for (int nt = 0; nt < 4; nt++) {
            bf16x8 bfr = *(const bf16x8*)(bp + nt * 4096 + kdi);
            acc[nt] = __builtin_amdgcn_mfma_f32_16x16x32_bf16(af, bfr, acc[nt], 0, 0, 0);
        }
    }

    const bool isQ = (by < 4), isK = (by >= 4) && (by < 8);
#pragma unroll
    for (int nt = 0; nt < 4; nt++) {
        const int c = nt * 16 + l15;
        const float bias = b[n0 + c];
#pragma unroll
        for (int r = 0; r < 4; r++) {
            const int lr = wv * 16 + quad * 4 + r;
            float val = acc[nt][r] + bias;
            if (isQ) val *= RS;
            tile[isK ? ksig(lr) : lr][c] = f2bf(val);
        }
    }
    __syncthreads();

    const int t = threadIdx.x;
    if (by < 8) {
        const int hh = t >> 7, i = t & 127;
        ushort* dst = isQ ? Qb + ((size_t)(by * 2 + hh) * L + m0b) * 32
                          : Kb + ((size_t)((by - 4) * 2 + hh) * L + m0b) * 32;
#pragma unroll
        for (int k = 0; k < 2; k++) {
            const int ci = i + k * 128;               // chunk: dest ushorts [ci*8, ci*8+8)
            const int row = ci >> 2, wc = (ci & 3) * 8;
            *(bf16x8*)(dst + ci * 8) = *(const bf16x8*)(&tile[row][hh * 32 + wc]);
        }
    } else {
        const int c = t & 63, rh = t >> 6;
        const int vc = n0 - 512 + c;
        ushort tmp[16];
#pragma unroll
        for (int r = 0; r < 16; r++) tmp[r] = tile[rh * 16 + r][c];
        ushort* dst = Vt + (size_t)vc * L + m0b + rh * 16;
        *(bf16x8*)dst       = *(const bf16x8*)tmp;
        *(bf16x8*)(dst + 8) = *(const bf16x8*)(tmp + 8);
    }
}

// ---------------- Kernel 2: flash attention, 8 chains / 16 waves -----------
// R14's 8-chain regression was the grid-256=1-block/CU occupancy cliff (8
// waves/CU), NOT registers (VGPR was 116 <= 128). Fix: 1024-thread blocks, 16
// waves each owning a 4-kt slice -> 16 waves/CU (4/SIMD) restored while
// keeping the 2x K/V/m2 amortization over R13 (32 blocks/head vs 64).
// f32-pair LUT kept (R15: -1.7us isolated). LDS 26.7+36.9 = 63.5 KB < 64.
// Epilogue: all 16 waves park each chain; wave c finalizes chain c (rotating
// finalizer, sums 16 LDS slots) - no serial single-wave growth.
__global__ __launch_bounds__(1024) void attn_kernel(
        const ushort* __restrict__ Qb, const ushort* __restrict__ Kb,
        const ushort* __restrict__ Vt, const unsigned char* __restrict__ m2,
        const float* __restrict__ edge_bias, ushort* __restrict__ Ob)
{
    __shared__ float2 lutp[196 * 17];   // 26.7 KB f32-pair LUT
    __shared__ float red[16 * 576];     // 36.9 KB reduction slots

    const int tid = threadIdx.x;
    const int lane = tid & 63, wv = tid >> 6;      // wv 0..15
    const int quad = lane >> 4, l15 = lane & 15;

    // qg-grouped XCD decode: all 8 heads of a 128-row group share xr -> XCD.
    const int bid = blockIdx.x;                    // 0..255
    const int xr = bid & 7, j = bid >> 3;          // j in [0,32)
    const int g  = xr * 4 + (j >> 3);              // 128-row group 0..31
    const int h  = j & 7;
    const int q0 = g * 128;
    const int kt0 = wv * 4;                        // this wave's 4-kt slice

    // per-head f32-pair LUT: entry p, copy c at float2 slot 17p+c
    for (int p = tid; p < 196; p += 1024) {
        const int e1 = (p * 2341) >> 15;           // p / 14 for p < 196
        const int e2 = p - 14 * e1;
        float2 v;
        v.x = edge_bias[e1 * H + h] * LOG2E;
        v.y = edge_bias[e2 * H + h] * LOG2E;
#pragma unroll
        for (int c = 0; c < 17; c++) lutp[p * 17 + c] = v;
    }
    __syncthreads();

    bf16x8 qf[8];
#pragma unroll
    for (int c = 0; c < 8; c++)
        qf[c] = *(const bf16x8*)(Qb + (h * L + q0 + c * 16 + l15) * DH + quad * 8);
    const char* lutb = (const char*)lutp + l15 * 8;   // per-lane copy base (8B)

    const ushort* Kl = Kb + h * L * DH + kt0 * 64 * DH + l15 * DH + quad * 8;
    const ushort* Va = Vt + (h * DH + l15) * L + kt0 * 64 + quad * 8;
    const ushort* Vb = Vt + (h * DH + 16 + l15) * L + kt0 * 64 + quad * 8;
    const unsigned char* mp = m2 + (size_t)(8 * g) * 65536
                            + (size_t)kt0 * 1024 + lane * 16;

    f32x4 o0[8] = {}, o1[8] = {}, os[8] = {};
    bf16x8 ones;
#pragma unroll
    for (int i = 0; i < 8; i++) ones[i] = (short)0x3F80;   // 1.0 bf16

    for (int kt = 0; kt < 4; kt++) {
        unsigned int m[8][4];
#pragma unroll
        for (int c = 0; c < 8; c++) {
            const int4 t4 = *(const int4*)(mp + (size_t)c * 65536 + kt * 1024);
            m[c][0] = (unsigned int)t4.x; m[c][1] = (unsigned int)t4.y;
            m[c][2] = (unsigned int)t4.z; m[c][3] = (unsigned int)t4.w;
        }

#pragma unroll
        for (int half = 0; half < 2; half++) {
            union { bf16x8 v; unsigned int u[4]; } pf[8];
#pragma unroll
            for (int nt2 = 0; nt2 < 2; nt2++) {
                const int nt = half * 2 + nt2;
                bf16x8 kf = *(const bf16x8*)(Kl + (kt * 64 + nt * 16) * DH);
#pragma unroll
                for (int c = 0; c < 8; c++) {
                    f32x4 z = {};
                    f32x4 sv = __builtin_amdgcn_mfma_f32_16x16x32_bf16(kf, qf[c], z, 0, 0, 0);
                    const unsigned int w = m[c][nt];
                    const float2 d0 = *(const float2*)(lutb + (w & 0xFFFFu));
                    const float2 d1 = *(const float2*)(lutb + (w >> 16));
                    float e0 = __builtin_amdgcn_exp2f(sv[0] + d0.x);
                    float e1 = __builtin_amdgcn_exp2f(sv[1] + d0.y);
                    float e2 = __builtin_amdgcn_exp2f(sv[2] + d1.x);
                    float e3 = __builtin_amdgcn_exp2f(sv[3] + d1.y);
                    pf[c].u[nt2 * 2]     = pkbf(e0, e1);
                    pf[c].u[nt2 * 2 + 1] = pkbf(e2, e3);
                }
            }
            bf16x8 va = *(const bf16x8*)(Va + kt * 64 + half * 32);
            bf16x8 vb = *(const bf16x8*)(Vb + kt * 64 + half * 32);
            __builtin_amdgcn_s_setprio(1);
#pragma unroll
            for (int c = 0; c < 8; c++) {
                o0[c] = __builtin_amdgcn_mfma_f32_16x16x32_bf16(va,   pf[c].v, o0[c], 0, 0, 0);
                o1[c] = __builtin_amdgcn_mfma_f32_16x16x32_bf16(vb,   pf[c].v, o1[c], 0, 0, 0);
                os[c] = __builtin_amdgcn_mfma_f32_16x16x32_bf16(ones, pf[c].v, os[c], 0, 0, 0);
            }
            __builtin_amdgcn_s_setprio(0);
        }
    }

    // ---- 8-phase reduction: all 16 waves park chain c; wave c finalizes ----
#pragma unroll
    for (int c = 0; c < 8; c++) {
        {
            float* s = red + wv * 576;
            *(f32x4*)(s +       lane * 4) = o0[c];
            *(f32x4*)(s + 256 + lane * 4) = o1[c];
            s[512 + lane] = os[c][0];
        }
        __syncthreads();
        if (wv == c) {
            f32x4 a0 = {}, a1 = {};
            float as = 0.f;
#pragma unroll
            for (int sl = 0; sl < 16; sl++) {
                const float* s = red + sl * 576;
                a0 += *(const f32x4*)(s +       lane * 4);
                a1 += *(const f32x4*)(s + 256 + lane * 4);
                as += s[512 + lane];
            }
            const float inv = 1.f / as;
            // FM Ob: 16-row tile mg = 8g+c; cols h*32 + {quad*4, 16+quad*4}
            ushort* obase = Ob + (size_t)(8 * g + c) * 4096 + l15 * 8 + (quad & 1) * 4;
            ushort* or0 = obase + (h * 4 + (quad >> 1)) * 128;
            ushort* or1 = obase + (h * 4 + 2 + (quad >> 1)) * 128;
            uint2 u;
            u.x = pkbf(a0[0] * inv, a0[1] * inv);
            u.y = pkbf(a0[2] * inv, a0[3] * inv);
            *(uint2*)or0 = u;
            u.x = pkbf(a1[0] * inv, a1[1] * inv);
            u.y = pkbf(a1[2] * inv, a1[3] * inv);
            *(uint2*)or1 = u;
        }
        __syncthreads();
    }
}

// ---------------- Kernel 3: output projection GEMM (R15-identical) ----------
__global__ __launch_bounds__(256) void oproj_kernel(
        const ushort* __restrict__ Ob, const ushort* __restrict__ wb,
        const float* __restrict__ b, float* __restrict__ out)
{
    const int lane = threadIdx.x & 63, wv = threadIdx.x >> 6;
    const int quad = lane >> 4, l15 = lane & 15;
    const int m0 = blockIdx.x * 64 + wv * 16;
    const int n0 = blockIdx.y * 16;
    const ushort* ap = Ob + (size_t)(blockIdx.x * 4 + wv) * 4096 + l15 * 8;
    const ushort* bp = wb + (size_t)blockIdx.y * 4096 + l15 * 8;

    f32x4 acc = {};
    for (int ks = 0; ks < 8; ks++) {
        const int kdi = (ks * 4 + quad) * 128;
        bf16x8 af  = *(const bf16x8*)(ap + kdi);
        bf16x8 bfr = *(const bf16x8*)(bp + kdi);
        acc = __builtin_amdgcn_mfma_f32_16x16x32_bf16(af, bfr, acc, 0, 0, 0);
    }
    const int j = n0 + l15;
    const float bias = b[j];
#pragma unroll
    for (int r = 0; r < 4; r++) {
        out[(m0 + quad * 4 + r) * D + j] = acc[r] + bias;
    }
}

extern "C" void kernel_launch(void* const* d_in, const int* in_sizes, int n_in,
                              void* d_out, int out_size, void* d_ws, size_t ws_size,
                              hipStream_t stream) {
    const float* x     = (const float*)d_in[0];
    const int*   mask  = (const int*)d_in[1];
    const float* in_w  = (const float*)d_in[2];
    const float* in_b  = (const float*)d_in[3];
    const float* out_w = (const float*)d_in[4];
    const float* out_b = (const float*)d_in[5];
    const float* eb    = (const float*)d_in[6];

    ushort* ws = (ushort*)d_ws;
    ushort* Qb  = ws;
    ushort* Kb  = Qb + H * L * DH;             // sigma-permuted rows
    ushort* Vt  = Kb + H * L * DH;
    ushort* xb  = Vt + H * L * DH;             // x bf16 FM (qkv staging)
    ushort* wib = xb + L * D;
    ushort* wob = wib + 3 * D * D;
    unsigned char* m2 = (unsigned char*)(wob + D * D);   // 16 MB pair-index stream
    ushort* Ob = (ushort*)(m2 + (size_t)L * L);          // normalized bf16 attn out (FM)
    float* out = (float*)d_out;

    pack_kernel<<<dim3(1152), 256, 0, stream>>>(mask, x, in_w, out_w,
                                                (unsigned int*)m2, xb, wib, wob);
    qkv_kernel<<<dim3(64, 12), 256, 0, stream>>>(xb, wib, in_b, Qb, Kb, Vt);
    attn_kernel<<<dim3(256), 1024, 0, stream>>>(Qb, Kb, Vt, m2, eb, Ob);
    oproj_kernel<<<dim3(64, 16), 256, 0, stream>>>(Ob, wob, out_b, out);
}

// Round 17
// 158.328 us; speedup vs baseline: 2.2682x; 2.2682x over previous
//
#include <hip/hip_runtime.h>
#include <hip/hip_bf16.h>
#include <string.h>

#define L 4096
#define D 256
#define H 8
#define DH 32

typedef __attribute__((ext_vector_type(8))) short bf16x8;
typedef __attribute__((ext_vector_type(4))) float f32x4;

#define LOG2E 1.4426950408889634f
#define RS (0.17677669529663688f * LOG2E)   // 1/sqrt(DH) * log2(e), folded into Q

__device__ __forceinline__ ushort f2bf(float f) {
    union { float f; unsigned int i; } v; v.f = f;
    unsigned int x = v.i;
    return (ushort)((x + 0x7fffu + ((x >> 16) & 1u)) >> 16);   // RNE
}
__device__ __forceinline__ bf16x8 cvt8(const float* p) {
    float4 a = *(const float4*)p;
    float4 b = *(const float4*)(p + 4);
    bf16x8 r;
    r[0] = (short)f2bf(a.x); r[1] = (short)f2bf(a.y);
    r[2] = (short)f2bf(a.z); r[3] = (short)f2bf(a.w);
    r[4] = (short)f2bf(b.x); r[5] = (short)f2bf(b.y);
    r[6] = (short)f2bf(b.z); r[7] = (short)f2bf(b.w);
    return r;
}
// pack two fp32 -> bf16x2 dword; native v_cvt_pk_bf16_f32 on gfx950
__device__ __forceinline__ unsigned int pkbf(float a, float b) {
    float2 t; t.x = a; t.y = b;
    __hip_bfloat162 r = __float22bfloat162_rn(t);
    unsigned int u; memcpy(&u, &r, 4);
    return u;
}

// sigma: logical key u (0..63) -> K storage row within its 64-block.
__device__ __forceinline__ int ksig(int u) {
    return 32 * (u >> 5) + 16 * ((u >> 2) & 1) + 4 * ((u >> 3) & 3) + (u & 3);
}

// Fragment-major (FM) layout for MFMA operand matrices (R rows x C cols bf16):
//   elem(r,c) at ((r>>4)*(C/8) + (c>>3))*128 + (r&15)*8 + (c&7)
// A wave's fragment load is ONE contiguous 1KB transaction (R8: -14.5 us).

// ---------------- Kernel 0: prepack ----------------
// m2 payload: 2x 16-bit pair byte-offsets (e_i*14+e_j)*136 into the stride-17
// f32-PAIR LUT (8B entries). Dword positions unchanged.
__global__ __launch_bounds__(256) void pack_kernel(
        const int* __restrict__ mask, const float* __restrict__ x,
        const float* __restrict__ wi, const float* __restrict__ wo,
        unsigned int* __restrict__ m2, ushort* __restrict__ xb,
        ushort* __restrict__ wib, ushort* __restrict__ wob)
{
    const int b = blockIdx.x;
    const int tid = threadIdx.x;
    if (b < 512) {
        __shared__ unsigned int rb[8 * 1025];
        const int4* src = (const int4*)(mask + (size_t)b * 8 * 4096);
#pragma unroll
        for (int i = 0; i < 32; i++) {
            const int g = i * 256 + tid;
            int4 v = src[g];
            rb[(g >> 10) * 1025 + (g & 1023)] =
                ((unsigned int)(v.x & 15) << 4)  | ((unsigned int)(v.y & 15) << 12) |
                ((unsigned int)(v.z & 15) << 20) | ((unsigned int)(v.w & 15) << 28);
        }
        __syncthreads();
        const int t = b >> 1, half = b & 1;
#pragma unroll
        for (int i = 0; i < 32; i++) {
            const int dd = i * 256 + tid;
            const int nt = dd & 3, s = (dd >> 2) & 7, qd = (dd >> 5) & 3, kt = dd >> 7;
            const unsigned int w =
                rb[s * 1025 + kt * 16 + 8 * (nt >> 1) + 2 * qd + (nt & 1)];
            const unsigned int e0 = (w >> 4) & 15u, e1 = (w >> 12) & 15u;
            const unsigned int e2 = (w >> 20) & 15u, e3 = w >> 28;
            const unsigned int p01 = e0 * 14u + e1, p23 = e2 * 14u + e3;
            m2[(size_t)t * 16384 + kt * 256 + (qd * 16 + 8 * half + s) * 4 + nt] =
                (p01 * 136u) | ((p23 * 136u) << 16);
        }
    } else if (b < 1024) {
        const int g = (b - 512) * 256 + tid;
        const int l = g & 15, kd = (g >> 4) & 31, mg = g >> 9;
        ((bf16x8*)xb)[g] = cvt8(x + (mg * 16 + l) * 256 + kd * 8);
    } else if (b < 1120) {
        const int g = (b - 1024) * 256 + tid;           // 768x256 FM
        const int l = g & 15, kd = (g >> 4) & 31, mg = g >> 9;
        ((bf16x8*)wib)[g] = cvt8(wi + (mg * 16 + l) * 256 + kd * 8);
    } else {
        const int g = (b - 1120) * 256 + tid;           // 256x256 FM
        const int l = g & 15, kd = (g >> 4) & 31, mg = g >> 9;
        ((bf16x8*)wob)[g] = cvt8(wo + (mg * 16 + l) * 256 + kd * 8);
    }
}

// ---------------- Kernel 1: QKV projection ----------------
__global__ __launch_bounds__(256) void qkv_kernel(
        const ushort* __restrict__ xb, const ushort* __restrict__ wb,
        const float* __restrict__ b,
        ushort* __restrict__ Qb, ushort* __restrict__ Kb, ushort* __restrict__ Vt)
{
    __shared__ ushort tile[64][72];   // 9.2 KB; row stride 144B (16B-aligned)

    const int lane = threadIdx.x & 63, wv = threadIdx.x >> 6;
    const int quad = lane >> 4, l15 = lane & 15;
    const int m0b = blockIdx.x * 64;
    const int by = blockIdx.y;            // 0-3: Q, 4-7: K, 8-11: V
    const int n0 = by * 64;
    const ushort* ap = xb + (size_t)(blockIdx.x * 4 + wv) * 4096 + l15 * 8;
    const ushort* bp = wb + (size_t)(by * 4) * 4096 + l15 * 8;

    f32x4 acc[4] = {};
    for (int ks = 0; ks < 8; ks++) {
        const int kdi = (ks * 4 + quad) * 128;
        bf16x8 af = *(const bf16x8*)(ap + kdi);
#pragma unroll
        for (int nt = 0; nt < 4; nt++) {
            bf16x8 bfr = *(const bf16x8*)(bp + nt * 4096 + kdi);
            acc[nt] = __builtin_amdgcn_mfma_f32_16x16x32_bf16(af, bfr, acc[nt], 0, 0, 0);
        }
    }

    const bool isQ = (by < 4), isK = (by >= 4) && (by < 8);
#pragma unroll
    for (int nt = 0; nt < 4; nt++) {
        const int c = nt * 16 + l15;
        const float bias = b[n0 + c];
#pragma unroll
        for (int r = 0; r < 4; r++) {
            const int lr = wv * 16 + quad * 4 + r;
            float val = acc[nt][r] + bias;
            if (isQ) val *= RS;
            tile[isK ? ksig(lr) : lr][c] = f2bf(val);
        }
    }
    __syncthreads();

    const int t = threadIdx.x;
    if (by < 8) {
        const int hh = t >> 7, i = t & 127;
        ushort* dst = isQ ? Qb + ((size_t)(by * 2 + hh) * L + m0b) * 32
                          : Kb + ((size_t)((by - 4) * 2 + hh) * L + m0b) * 32;
#pragma unroll
        for (int k = 0; k < 2; k++) {
            const int ci = i + k * 128;               // chunk: dest ushorts [ci*8, ci*8+8)
            const int row = ci >> 2, wc = (ci & 3) * 8;
            *(bf16x8*)(dst + ci * 8) = *(const bf16x8*)(&tile[row][hh * 32 + wc]);
        }
    } else {
        const int c = t & 63, rh = t >> 6;
        const int vc = n0 - 512 + c;
        ushort tmp[16];
#pragma unroll
        for (int r = 0; r < 16; r++) tmp[r] = tile[rh * 16 + r][c];
        ushort* dst = Vt + (size_t)vc * L + m0b + rh * 16;
        *(bf16x8*)dst       = *(const bf16x8*)tmp;
        *(bf16x8*)(dst + 8) = *(const bf16x8*)(tmp + 8);
    }
}

// ---------------- Kernel 2: flash attention, 4 chains + f32-pair LUT -------
// Session-final attn configuration (R15-verified 46.8 us): 4 q-tile chains
// per wave (R13 mechanism: K/V/m2 amortization + ILP), f32-pair LUT
// (ds_read_b64 biases, R15: -1.7 us isolated), VGPR 64, 2 blocks/CU.
// 8-chain variants failed twice on resource cliffs (R14: occupancy at 512
// threads; R16: 662 MB scratch spills at 1024 threads) - amortization is
// exhausted at 4 chains.
__global__ __launch_bounds__(512) void attn_kernel(
        const ushort* __restrict__ Qb, const ushort* __restrict__ Kb,
        const ushort* __restrict__ Vt, const unsigned char* __restrict__ m2,
        const float* __restrict__ edge_bias, ushort* __restrict__ Ob)
{
    __shared__ float2 lutp[196 * 17];   // 26.7 KB f32-pair LUT
    __shared__ float red[7 * 576];      // 16.1 KB reduction slots

    const int tid = threadIdx.x;
    const int lane = tid & 63, wv = tid >> 6;
    const int quad = lane >> 4, l15 = lane & 15;

    // qg-grouped XCD decode: all 8 heads of a 64-row group share bid%8 -> XCD.
    const int bid = blockIdx.x;                    // 0..511
    const int xr = bid & 7, j = bid >> 3;          // j in [0,64)
    const int g  = xr * 8 + (j >> 3);              // 64-row group 0..63
    const int h  = j & 7;
    const int q0 = g * 64;
    const int kt0 = wv * 8;                        // this wave's 8-kt slice

    // per-head f32-pair LUT: entry p, copy c at float2 slot 17p+c
    for (int p = tid; p < 196; p += 512) {
        const int e1 = (p * 2341) >> 15;           // p / 14 for p < 196
        const int e2 = p - 14 * e1;
        float2 v;
        v.x = edge_bias[e1 * H + h] * LOG2E;
        v.y = edge_bias[e2 * H + h] * LOG2E;
#pragma unroll
        for (int c = 0; c < 17; c++) lutp[p * 17 + c] = v;
    }
    __syncthreads();

    bf16x8 qf[4];
#pragma unroll
    for (int c = 0; c < 4; c++)
        qf[c] = *(const bf16x8*)(Qb + (h * L + q0 + c * 16 + l15) * DH + quad * 8);
    const char* lutb = (const char*)lutp + l15 * 8;   // per-lane copy base (8B)

    const ushort* Kl = Kb + h * L * DH + kt0 * 64 * DH + l15 * DH + quad * 8;
    const ushort* Va = Vt + (h * DH + l15) * L + kt0 * 64 + quad * 8;
    const ushort* Vb = Vt + (h * DH + 16 + l15) * L + kt0 * 64 + quad * 8;
    const unsigned char* mp = m2 + (size_t)(4 * g) * 65536
                            + (size_t)kt0 * 1024 + lane * 16;

    f32x4 o0[4] = {}, o1[4] = {}, os[4] = {};
    bf16x8 ones;
#pragma unroll
    for (int i = 0; i < 8; i++) ones[i] = (short)0x3F80;   // 1.0 bf16

    for (int kt = 0; kt < 8; kt++) {
        unsigned int m[4][4];
#pragma unroll
        for (int c = 0; c < 4; c++) {
            const int4 t4 = *(const int4*)(mp + (size_t)c * 65536 + kt * 1024);
            m[c][0] = (unsigned int)t4.x; m[c][1] = (unsigned int)t4.y;
            m[c][2] = (unsigned int)t4.z; m[c][3] = (unsigned int)t4.w;
        }

#pragma unroll
        for (int half = 0; half < 2; half++) {
            union { bf16x8 v; unsigned int u[4]; } pf[4];
#pragma unroll
            for (int nt2 = 0; nt2 < 2; nt2++) {
                const int nt = half * 2 + nt2;
                bf16x8 kf = *(const bf16x8*)(Kl + (kt * 64 + nt * 16) * DH);
#pragma unroll
                for (int c = 0; c < 4; c++) {
                    f32x4 z = {};
                    f32x4 sv = __builtin_amdgcn_mfma_f32_16x16x32_bf16(kf, qf[c], z, 0, 0, 0);
                    const unsigned int w = m[c][nt];
                    const float2 d0 = *(const float2*)(lutb + (w & 0xFFFFu));
                    const float2 d1 = *(const float2*)(lutb + (w >> 16));
                    float e0 = __builtin_amdgcn_exp2f(sv[0] + d0.x);
                    float e1 = __builtin_amdgcn_exp2f(sv[1] + d0.y);
                    float e2 = __builtin_amdgcn_exp2f(sv[2] + d1.x);
                    float e3 = __builtin_amdgcn_exp2f(sv[3] + d1.y);
                    pf[c].u[nt2 * 2]     = pkbf(e0, e1);
                    pf[c].u[nt2 * 2 + 1] = pkbf(e2, e3);
                }
            }
            bf16x8 va = *(const bf16x8*)(Va + kt * 64 + half * 32);
            bf16x8 vb = *(const bf16x8*)(Vb + kt * 64 + half * 32);
            __builtin_amdgcn_s_setprio(1);
#pragma unroll
            for (int c = 0; c < 4; c++) {
                o0[c] = __builtin_amdgcn_mfma_f32_16x16x32_bf16(va,   pf[c].v, o0[c], 0, 0, 0);
                o1[c] = __builtin_amdgcn_mfma_f32_16x16x32_bf16(vb,   pf[c].v, o1[c], 0, 0, 0);
                os[c] = __builtin_amdgcn_mfma_f32_16x16x32_bf16(ones, pf[c].v, os[c], 0, 0, 0);
            }
            __builtin_amdgcn_s_setprio(0);
        }
    }

    // ---- 4-phase in-block KT reduction (red[] reused per chain) ----
#pragma unroll
    for (int c = 0; c < 4; c++) {
        if (wv > 0) {
            float* s = red + (wv - 1) * 576;
            *(f32x4*)(s +       lane * 4) = o0[c];
            *(f32x4*)(s + 256 + lane * 4) = o1[c];
            s[512 + lane] = os[c][0];
        }
        __syncthreads();
        if (wv == 0) {
#pragma unroll
            for (int sl = 0; sl < 7; sl++) {
                const float* s = red + sl * 576;
                o0[c] += *(const f32x4*)(s +       lane * 4);
                o1[c] += *(const f32x4*)(s + 256 + lane * 4);
                os[c][0] += s[512 + lane];
            }
            const float inv = 1.f / os[c][0];
            // FM Ob: 16-row tile mg = 4g+c; cols h*32 + {quad*4, 16+quad*4}
            ushort* obase = Ob + (size_t)(4 * g + c) * 4096 + l15 * 8 + (quad & 1) * 4;
            ushort* or0 = obase + (h * 4 + (quad >> 1)) * 128;
            ushort* or1 = obase + (h * 4 + 2 + (quad >> 1)) * 128;
            uint2 u;
            u.x = pkbf(o0[c][0] * inv, o0[c][1] * inv);
            u.y = pkbf(o0[c][2] * inv, o0[c][3] * inv);
            *(uint2*)or0 = u;
            u.x = pkbf(o1[c][0] * inv, o1[c][1] * inv);
            u.y = pkbf(o1[c][2] * inv, o1[c][3] * inv);
            *(uint2*)or1 = u;
        }
        __syncthreads();
    }
}

// ---------------- Kernel 3: output projection GEMM, 16x16 per wave ----------
__global__ __launch_bounds__(256) void oproj_kernel(
        const ushort* __restrict__ Ob, const ushort* __restrict__ wb,
        const float* __restrict__ b, float* __restrict__ out)
{
    const int lane = threadIdx.x & 63, wv = threadIdx.x >> 6;
    const int quad = lane >> 4, l15 = lane & 15;
    const int m0 = blockIdx.x * 64 + wv * 16;
    const int n0 = blockIdx.y * 16;
    const ushort* ap = Ob + (size_t)(blockIdx.x * 4 + wv) * 4096 + l15 * 8;
    const ushort* bp = wb + (size_t)blockIdx.y * 4096 + l15 * 8;

    f32x4 acc = {};
    for (int ks = 0; ks < 8; ks++) {
        const int kdi = (ks * 4 + quad) * 128;
        bf16x8 af  = *(const bf16x8*)(ap + kdi);
        bf16x8 bfr = *(const bf16x8*)(bp + kdi);
        acc = __builtin_amdgcn_mfma_f32_16x16x32_bf16(af, bfr, acc, 0, 0, 0);
    }
    const int j = n0 + l15;
    const float bias = b[j];
#pragma unroll
    for (int r = 0; r < 4; r++) {
        out[(m0 + quad * 4 + r) * D + j] = acc[r] + bias;
    }
}

extern "C" void kernel_launch(void* const* d_in, const int* in_sizes, int n_in,
                              void* d_out, int out_size, void* d_ws, size_t ws_size,
                              hipStream_t stream) {
    const float* x     = (const float*)d_in[0];
    const int*   mask  = (const int*)d_in[1];
    const float* in_w  = (const float*)d_in[2];
    const float* in_b  = (const float*)d_in[3];
    const float* out_w = (const float*)d_in[4];
    const float* out_b = (const float*)d_in[5];
    const float* eb    = (const float*)d_in[6];

    ushort* ws = (ushort*)d_ws;
    ushort* Qb  = ws;
    ushort* Kb  = Qb + H * L * DH;             // sigma-permuted rows
    ushort* Vt  = Kb + H * L * DH;
    ushort* xb  = Vt + H * L * DH;             // x bf16 FM (qkv staging)
    ushort* wib = xb + L * D;
    ushort* wob = wib + 3 * D * D;
    unsigned char* m2 = (unsigned char*)(wob + D * D);   // 16 MB pair-index stream
    ushort* Ob = (ushort*)(m2 + (size_t)L * L);          // normalized bf16 attn out (FM)
    float* out = (float*)d_out;

    pack_kernel<<<dim3(1152), 256, 0, stream>>>(mask, x, in_w, out_w,
                                                (unsigned int*)m2, xb, wib, wob);
    qkv_kernel<<<dim3(64, 12), 256, 0, stream>>>(xb, wib, in_b, Qb, Kb, Vt);
    attn_kernel<<<dim3(512), 512, 0, stream>>>(Qb, Kb, Vt, m2, eb, Ob);
    oproj_kernel<<<dim3(64, 16), 256, 0, stream>>>(Ob, wob, out_b, out);
}